// Round 8
// baseline (492.110 us; speedup 1.0000x reference)
//
#include <hip/hip_runtime.h>

#define NHEADS 4
#define NEG_SLOPE 0.2f
#define EPS_LN 1e-5f

// ---------------- CSR build ----------------
__global__ __launch_bounds__(256) void k_init_deg(int* __restrict__ deg, int n) {
    int i = blockIdx.x * 256 + threadIdx.x;
    if (i < n) deg[i] = 1;  // self-loop
}

__global__ __launch_bounds__(256) void k_count(const int* __restrict__ dst, int* __restrict__ deg, int e) {
    int i = blockIdx.x * 256 + threadIdx.x;
    if (i < e) atomicAdd(&deg[dst[i]], 1);
}

__global__ __launch_bounds__(256) void k_scan1(const int* __restrict__ deg, int* __restrict__ rs,
                                               int* __restrict__ bsum, int n) {
    __shared__ int tmp[256];
    int tx = threadIdx.x;
    int i = blockIdx.x * 256 + tx;
    int v = (i < n) ? deg[i] : 0;
    tmp[tx] = v;
    __syncthreads();
    for (int off = 1; off < 256; off <<= 1) {
        int t = (tx >= off) ? tmp[tx - off] : 0;
        __syncthreads();
        tmp[tx] += t;
        __syncthreads();
    }
    if (i < n) rs[i] = tmp[tx] - v;
    if (tx == 255) bsum[blockIdx.x] = tmp[255];
}

__global__ __launch_bounds__(256) void k_scan2(int* __restrict__ bsum, int nb) {
    __shared__ int tmp[256];
    int tx = threadIdx.x;
    int v = (tx < nb) ? bsum[tx] : 0;
    tmp[tx] = v;
    __syncthreads();
    for (int off = 1; off < 256; off <<= 1) {
        int t = (tx >= off) ? tmp[tx - off] : 0;
        __syncthreads();
        tmp[tx] += t;
        __syncthreads();
    }
    if (tx < nb) bsum[tx] = tmp[tx] - v;
}

__global__ __launch_bounds__(256) void k_scan3(int* __restrict__ rs, int* __restrict__ cur,
                                               const int* __restrict__ bsum, int n, int total) {
    int i = blockIdx.x * 256 + threadIdx.x;
    if (i < n) {
        int r = rs[i] + bsum[blockIdx.x];
        rs[i] = r;
        cur[i] = r;
    }
    if (i == 0) rs[n] = total;
}

__global__ __launch_bounds__(256) void k_scatter(const int* __restrict__ src, const int* __restrict__ dst,
                                                 int* __restrict__ cur, int* __restrict__ col, int e, int n) {
    int i = blockIdx.x * 256 + threadIdx.x;
    if (i < e + n) {
        int s, d;
        if (i < e) { s = src[i]; d = dst[i]; }
        else       { s = i - e;  d = i - e;  }
        int p = atomicAdd(&cur[d], 1);
        col[p] = s;
    }
}

__device__ __forceinline__ unsigned pack_bf16(float a, float b) {
    unsigned ua = __float_as_uint(a); ua += 0x7fffu + ((ua >> 16) & 1u);
    unsigned ub = __float_as_uint(b); ub += 0x7fffu + ((ub >> 16) & 1u);
    return (ua >> 16) | (ub & 0xffff0000u);
}

// ---------------- 128x128-tile double-buffered GEMM (fp32) -> bf16 h + attn coefs ----------------
// C = A[M,K] @ B[K,256]; grid (ceil(M/128), 2); blockIdx.y = 128-col slab = heads {2y, 2y+1}.
// Quadrant 8x8 micro-tile (stride-4 LDS reads -> 2-way, free). DOUBLE-BUFFERED staging:
// stage s: issue global loads for s+1 (vmcnt in flight) -> compute from LDS[s&1] ->
// write prefetch to LDS[(s+1)&1] -> one barrier. Global latency hides under 2048 FMA cyc.
__global__ __launch_bounds__(256) void k_gemm_gat(const float* __restrict__ A, const float* __restrict__ B,
                                                  const float* __restrict__ asrc, const float* __restrict__ adst,
                                                  unsigned* __restrict__ Hb, float* __restrict__ es,
                                                  float* __restrict__ ed, int M, int K) {
    __shared__ float As[2][16][132];
    __shared__ float Bs[2][16][132];
    int tid = threadIdx.x;
    int m0 = blockIdx.x * 128;
    int n0 = blockIdx.y * 128;
    int ty = tid >> 4, tx = tid & 15;
    int ar = tid >> 1;            // A-stage row 0..127
    int ak = (tid & 1) * 8;       // A-stage k base (0 or 8)
    int bk = tid >> 4;            // B-stage k row 0..15
    int bn = (tid & 15) * 4;      // B-stage col base (stride-4: 2-way, free)
    int am = m0 + ar;
    bool aok = am < M;
    const float* arow = A + (size_t)am * K;
    float acc[8][8] = {};
    const int S = K >> 4;
    // prologue: stage 0 -> LDS[0]
    float4 pa0 = make_float4(0.f,0.f,0.f,0.f), pa1 = pa0;
    if (aok) { pa0 = *(const float4*)&arow[ak]; pa1 = *(const float4*)&arow[ak + 4]; }
    float4 pb0 = *(const float4*)&B[(size_t)bk * 256 + n0 + bn];
    float4 pb1 = *(const float4*)&B[(size_t)bk * 256 + n0 + bn + 64];
    As[0][ak + 0][ar] = pa0.x; As[0][ak + 1][ar] = pa0.y; As[0][ak + 2][ar] = pa0.z; As[0][ak + 3][ar] = pa0.w;
    As[0][ak + 4][ar] = pa1.x; As[0][ak + 5][ar] = pa1.y; As[0][ak + 6][ar] = pa1.z; As[0][ak + 7][ar] = pa1.w;
    *(float4*)&Bs[0][bk][bn]      = pb0;
    *(float4*)&Bs[0][bk][bn + 64] = pb1;
    __syncthreads();
    for (int s = 0; s < S; s++) {
        int cb = s & 1;
        float4 na0, na1, nb0, nb1;
        if (s + 1 < S) {
            int kn = (s + 1) << 4;
            na0 = make_float4(0.f,0.f,0.f,0.f); na1 = na0;
            if (aok) { na0 = *(const float4*)&arow[kn + ak]; na1 = *(const float4*)&arow[kn + ak + 4]; }
            nb0 = *(const float4*)&B[(size_t)(kn + bk) * 256 + n0 + bn];
            nb1 = *(const float4*)&B[(size_t)(kn + bk) * 256 + n0 + bn + 64];
        }
#pragma unroll
        for (int k = 0; k < 16; k++) {
            float4 x0 = *(const float4*)&As[cb][k][ty * 4];
            float4 x1 = *(const float4*)&As[cb][k][64 + ty * 4];
            float4 y0 = *(const float4*)&Bs[cb][k][tx * 4];
            float4 y1 = *(const float4*)&Bs[cb][k][64 + tx * 4];
            float av[8] = {x0.x, x0.y, x0.z, x0.w, x1.x, x1.y, x1.z, x1.w};
            float bv[8] = {y0.x, y0.y, y0.z, y0.w, y1.x, y1.y, y1.z, y1.w};
#pragma unroll
            for (int i = 0; i < 8; i++)
#pragma unroll
                for (int j = 0; j < 8; j++)
                    acc[i][j] += av[i] * bv[j];
        }
        if (s + 1 < S) {
            int wb = cb ^ 1;
            As[wb][ak + 0][ar] = na0.x; As[wb][ak + 1][ar] = na0.y; As[wb][ak + 2][ar] = na0.z; As[wb][ak + 3][ar] = na0.w;
            As[wb][ak + 4][ar] = na1.x; As[wb][ak + 5][ar] = na1.y; As[wb][ak + 6][ar] = na1.z; As[wb][ak + 7][ar] = na1.w;
            *(float4*)&Bs[wb][bk][bn]      = nb0;
            *(float4*)&Bs[wb][bk][bn + 64] = nb1;
        }
        __syncthreads();
    }
    // epilogue: es/ed per head (fp32-exact, butterfly over tx bits 1/2/4/8) + bf16 h write
    int h0 = blockIdx.y * 2, h1 = h0 + 1;
    float a0v[4], d0v[4], a1v[4], d1v[4];
#pragma unroll
    for (int j = 0; j < 4; j++) {
        a0v[j] = asrc[h0 * 64 + tx * 4 + j];
        d0v[j] = adst[h0 * 64 + tx * 4 + j];
        a1v[j] = asrc[h1 * 64 + tx * 4 + j];
        d1v[j] = adst[h1 * 64 + tx * 4 + j];
    }
#pragma unroll
    for (int r = 0; r < 2; r++) {
#pragma unroll
        for (int i = 0; i < 4; i++) {
            int ai = r * 4 + i;
            int m = m0 + r * 64 + ty * 4 + i;
            float se0 = 0.f, sd0 = 0.f, se1 = 0.f, sd1 = 0.f;
#pragma unroll
            for (int j = 0; j < 4; j++) {
                se0 += acc[ai][j] * a0v[j];     sd0 += acc[ai][j] * d0v[j];
                se1 += acc[ai][4 + j] * a1v[j]; sd1 += acc[ai][4 + j] * d1v[j];
            }
#pragma unroll
            for (int off = 1; off < 16; off <<= 1) {
                se0 += __shfl_xor(se0, off, 64); sd0 += __shfl_xor(sd0, off, 64);
                se1 += __shfl_xor(se1, off, 64); sd1 += __shfl_xor(sd1, off, 64);
            }
            if (m < M) {
                uint2 p0, p1;
                p0.x = pack_bf16(acc[ai][0], acc[ai][1]);
                p0.y = pack_bf16(acc[ai][2], acc[ai][3]);
                p1.x = pack_bf16(acc[ai][4], acc[ai][5]);
                p1.y = pack_bf16(acc[ai][6], acc[ai][7]);
                *(uint2*)&Hb[(size_t)m * 128 + h0 * 32 + tx * 2] = p0;
                *(uint2*)&Hb[(size_t)m * 128 + h1 * 32 + tx * 2] = p1;
                if (tx == 0) {
                    es[m * 4 + h0] = se0; ed[m * 4 + h0] = sd0;
                    es[m * 4 + h1] = se1; ed[m * 4 + h1] = sd1;
                }
            }
        }
    }
}

// ---------------- 128x128-tile double-buffered fp32 GEMM with bias (output projection) ----------------
__global__ __launch_bounds__(256) void k_gemm(const float* __restrict__ A, const float* __restrict__ B,
                                              const float* __restrict__ bias, float* __restrict__ C,
                                              int M, int N, int K) {
    __shared__ float As[2][16][132];
    __shared__ float Bs[2][16][132];
    int tid = threadIdx.x;
    int m0 = blockIdx.x * 128, n0 = blockIdx.y * 128;
    int ty = tid >> 4, tx = tid & 15;
    int ar = tid >> 1;
    int ak = (tid & 1) * 8;
    int bk = tid >> 4;
    int bn = (tid & 15) * 4;
    int am = m0 + ar;
    bool aok = am < M;
    const float* arow = A + (size_t)am * K;
    float acc[8][8] = {};
    const int S = K >> 4;
    float4 pa0 = make_float4(0.f,0.f,0.f,0.f), pa1 = pa0;
    if (aok) { pa0 = *(const float4*)&arow[ak]; pa1 = *(const float4*)&arow[ak + 4]; }
    float4 pb0 = *(const float4*)&B[(size_t)bk * N + n0 + bn];
    float4 pb1 = *(const float4*)&B[(size_t)bk * N + n0 + bn + 64];
    As[0][ak + 0][ar] = pa0.x; As[0][ak + 1][ar] = pa0.y; As[0][ak + 2][ar] = pa0.z; As[0][ak + 3][ar] = pa0.w;
    As[0][ak + 4][ar] = pa1.x; As[0][ak + 5][ar] = pa1.y; As[0][ak + 6][ar] = pa1.z; As[0][ak + 7][ar] = pa1.w;
    *(float4*)&Bs[0][bk][bn]      = pb0;
    *(float4*)&Bs[0][bk][bn + 64] = pb1;
    __syncthreads();
    for (int s = 0; s < S; s++) {
        int cb = s & 1;
        float4 na0, na1, nb0, nb1;
        if (s + 1 < S) {
            int kn = (s + 1) << 4;
            na0 = make_float4(0.f,0.f,0.f,0.f); na1 = na0;
            if (aok) { na0 = *(const float4*)&arow[kn + ak]; na1 = *(const float4*)&arow[kn + ak + 4]; }
            nb0 = *(const float4*)&B[(size_t)(kn + bk) * N + n0 + bn];
            nb1 = *(const float4*)&B[(size_t)(kn + bk) * N + n0 + bn + 64];
        }
#pragma unroll
        for (int k = 0; k < 16; k++) {
            float4 x0 = *(const float4*)&As[cb][k][ty * 4];
            float4 x1 = *(const float4*)&As[cb][k][64 + ty * 4];
            float4 y0 = *(const float4*)&Bs[cb][k][tx * 4];
            float4 y1 = *(const float4*)&Bs[cb][k][64 + tx * 4];
            float av[8] = {x0.x, x0.y, x0.z, x0.w, x1.x, x1.y, x1.z, x1.w};
            float bv[8] = {y0.x, y0.y, y0.z, y0.w, y1.x, y1.y, y1.z, y1.w};
#pragma unroll
            for (int i = 0; i < 8; i++)
#pragma unroll
                for (int j = 0; j < 8; j++)
                    acc[i][j] += av[i] * bv[j];
        }
        if (s + 1 < S) {
            int wb = cb ^ 1;
            As[wb][ak + 0][ar] = na0.x; As[wb][ak + 1][ar] = na0.y; As[wb][ak + 2][ar] = na0.z; As[wb][ak + 3][ar] = na0.w;
            As[wb][ak + 4][ar] = na1.x; As[wb][ak + 5][ar] = na1.y; As[wb][ak + 6][ar] = na1.z; As[wb][ak + 7][ar] = na1.w;
            *(float4*)&Bs[wb][bk][bn]      = nb0;
            *(float4*)&Bs[wb][bk][bn + 64] = nb1;
        }
        __syncthreads();
    }
    int nb0i = n0 + tx * 4, nb1i = n0 + 64 + tx * 4;
    float4 bia0 = *(const float4*)&bias[nb0i];
    float4 bia1 = *(const float4*)&bias[nb1i];
#pragma unroll
    for (int r = 0; r < 2; r++) {
#pragma unroll
        for (int i = 0; i < 4; i++) {
            int ai = r * 4 + i;
            int m = m0 + r * 64 + ty * 4 + i;
            if (m < M) {
                float4 r0, r1;
                r0.x = acc[ai][0] + bia0.x; r0.y = acc[ai][1] + bia0.y;
                r0.z = acc[ai][2] + bia0.z; r0.w = acc[ai][3] + bia0.w;
                r1.x = acc[ai][4] + bia1.x; r1.y = acc[ai][5] + bia1.y;
                r1.z = acc[ai][6] + bia1.z; r1.w = acc[ai][7] + bia1.w;
                *(float4*)&C[(size_t)m * N + nb0i] = r0;
                *(float4*)&C[(size_t)m * N + nb1i] = r1;
            }
        }
    }
}

// ---------------- fused GAT aggregate (bf16 gather) + head-mean + bias + LN + ReLU ----------------
// one wave per destination node; lane = (head, channel-quad). Unroll-4 with hoisted
// loads: 4 independent col->(es,Hb) chains in flight per wave for gather MLP.
__global__ __launch_bounds__(256) void k_gat_aggregate(const unsigned* __restrict__ Hb, const float* __restrict__ es,
                                                       const float* __restrict__ ed, const int* __restrict__ rs,
                                                       const int* __restrict__ col, const float* __restrict__ b,
                                                       const float* __restrict__ g, const float* __restrict__ be,
                                                       float* __restrict__ out, int n) {
    int node = blockIdx.x * 4 + (threadIdx.x >> 6);
    int lane = threadIdx.x & 63;
    if (node >= n) return;
    int head = lane >> 4;
    int cp = lane & 15;
    float edv = ed[node * 4 + head];
    float acc0 = 0.f, acc1 = 0.f, acc2 = 0.f, acc3 = 0.f, den = 0.f;
    int i0 = rs[node], i1 = rs[node + 1];
    int i = i0;
    for (; i + 3 < i1; i += 4) {
        int s0 = col[i], s1 = col[i + 1], s2 = col[i + 2], s3 = col[i + 3];
        float e0 = es[s0 * 4 + head];
        float e1 = es[s1 * 4 + head];
        float e2 = es[s2 * 4 + head];
        float e3 = es[s3 * 4 + head];
        uint2 u0 = *(const uint2*)&Hb[(size_t)s0 * 128 + lane * 2];
        uint2 u1 = *(const uint2*)&Hb[(size_t)s1 * 128 + lane * 2];
        uint2 u2 = *(const uint2*)&Hb[(size_t)s2 * 128 + lane * 2];
        uint2 u3 = *(const uint2*)&Hb[(size_t)s3 * 128 + lane * 2];
        e0 += edv; e1 += edv; e2 += edv; e3 += edv;
        e0 = fmaxf(e0, NEG_SLOPE * e0);
        e1 = fmaxf(e1, NEG_SLOPE * e1);
        e2 = fmaxf(e2, NEG_SLOPE * e2);
        e3 = fmaxf(e3, NEG_SLOPE * e3);
        float w0 = __expf(e0), w1 = __expf(e1), w2 = __expf(e2), w3 = __expf(e3);
        acc0 += w0 * __uint_as_float(u0.x << 16);
        acc1 += w0 * __uint_as_float(u0.x & 0xffff0000u);
        acc2 += w0 * __uint_as_float(u0.y << 16);
        acc3 += w0 * __uint_as_float(u0.y & 0xffff0000u);
        acc0 += w1 * __uint_as_float(u1.x << 16);
        acc1 += w1 * __uint_as_float(u1.x & 0xffff0000u);
        acc2 += w1 * __uint_as_float(u1.y << 16);
        acc3 += w1 * __uint_as_float(u1.y & 0xffff0000u);
        acc0 += w2 * __uint_as_float(u2.x << 16);
        acc1 += w2 * __uint_as_float(u2.x & 0xffff0000u);
        acc2 += w2 * __uint_as_float(u2.y << 16);
        acc3 += w2 * __uint_as_float(u2.y & 0xffff0000u);
        acc0 += w3 * __uint_as_float(u3.x << 16);
        acc1 += w3 * __uint_as_float(u3.x & 0xffff0000u);
        acc2 += w3 * __uint_as_float(u3.y << 16);
        acc3 += w3 * __uint_as_float(u3.y & 0xffff0000u);
        den += w0 + w1 + w2 + w3;
    }
    for (; i < i1; i++) {
        int s0 = col[i];
        float e0 = es[s0 * 4 + head] + edv;
        uint2 u0 = *(const uint2*)&Hb[(size_t)s0 * 128 + lane * 2];
        e0 = fmaxf(e0, NEG_SLOPE * e0);
        float w0 = __expf(e0);
        acc0 += w0 * __uint_as_float(u0.x << 16);
        acc1 += w0 * __uint_as_float(u0.x & 0xffff0000u);
        acc2 += w0 * __uint_as_float(u0.y << 16);
        acc3 += w0 * __uint_as_float(u0.y & 0xffff0000u);
        den += w0;
    }
    // softmax-normalize own head, then mean over heads via xor-16/32 butterflies
    float rd = 1.f / den;
    float r0 = acc0 * rd, r1 = acc1 * rd, r2 = acc2 * rd, r3 = acc3 * rd;
    r0 += __shfl_xor(r0, 16, 64); r1 += __shfl_xor(r1, 16, 64);
    r2 += __shfl_xor(r2, 16, 64); r3 += __shfl_xor(r3, 16, 64);
    r0 += __shfl_xor(r0, 32, 64); r1 += __shfl_xor(r1, 32, 64);
    r2 += __shfl_xor(r2, 32, 64); r3 += __shfl_xor(r3, 32, 64);
    float4 bb = *(const float4*)&b[cp * 4];
    float v0 = 0.25f * r0 + bb.x;
    float v1 = 0.25f * r1 + bb.y;
    float v2 = 0.25f * r2 + bb.z;
    float v3 = 0.25f * r3 + bb.w;
    // LayerNorm over 64 channels: reduce within the 16-lane head group (groups identical)
    float s = v0 + v1 + v2 + v3;
    float q = v0 * v0 + v1 * v1 + v2 * v2 + v3 * v3;
    for (int off = 1; off < 16; off <<= 1) {
        s += __shfl_xor(s, off, 64);
        q += __shfl_xor(q, off, 64);
    }
    float mean = s * (1.f / 64.f);
    float var = q * (1.f / 64.f) - mean * mean;
    float rinv = rsqrtf(var + EPS_LN);
    float4 gg = *(const float4*)&g[cp * 4];
    float4 ee = *(const float4*)&be[cp * 4];
    if (head == 0) {
        float4 y;
        y.x = fmaxf((v0 - mean) * rinv * gg.x + ee.x, 0.f);
        y.y = fmaxf((v1 - mean) * rinv * gg.y + ee.y, 0.f);
        y.z = fmaxf((v2 - mean) * rinv * gg.z + ee.z, 0.f);
        y.w = fmaxf((v3 - mean) * rinv * gg.w + ee.w, 0.f);
        *(float4*)&out[(size_t)node * 64 + cp * 4] = y;
    }
}

// ---------------- launch ----------------
extern "C" void kernel_launch(void* const* d_in, const int* in_sizes, int n_in,
                              void* d_out, int out_size, void* d_ws, size_t ws_size,
                              hipStream_t stream) {
    const float* x     = (const float*)d_in[0];
    const int*   eidx  = (const int*)d_in[1];
    const float* W1    = (const float*)d_in[2];
    const float* asrc1 = (const float*)d_in[3];
    const float* adst1 = (const float*)d_in[4];
    const float* b1    = (const float*)d_in[5];
    const float* g1    = (const float*)d_in[6];
    const float* be1   = (const float*)d_in[7];
    const float* W2    = (const float*)d_in[8];
    const float* asrc2 = (const float*)d_in[9];
    const float* adst2 = (const float*)d_in[10];
    const float* b2    = (const float*)d_in[11];
    const float* g2    = (const float*)d_in[12];
    const float* be2   = (const float*)d_in[13];
    const float* Wo    = (const float*)d_in[14];
    const float* bo    = (const float*)d_in[15];

    const int N = in_sizes[0] / 128;
    const int E = in_sizes[1] / 2;
    const int* srcp = eidx;
    const int* dstp = eidx + E;

    // workspace layout
    unsigned* hb   = (unsigned*)d_ws;                       // [N*128] bf16x2 (h1, then h3)
    float* h_small = (float*)(hb + (size_t)N * 128);        // [N,64] fp32 (h2, then h4)
    float* es      = h_small + (size_t)N * 64;              // [N,4]
    float* ed      = es + (size_t)N * 4;                    // [N,4]
    int* deg       = (int*)(ed + (size_t)N * 4);            // [N]
    int* rowstart  = deg + N;                               // [N+1]
    int* cursor    = rowstart + (N + 1);                    // [N]
    int* colarr    = cursor + N;                            // [E+N]
    int* bsum      = colarr + (size_t)(E + N);              // [<=256]

    const int nb = (N + 255) / 256;
    const int nwb = (N + 3) / 4;
    const int mt128 = (N + 127) / 128;

    // CSR build
    k_init_deg<<<nb, 256, 0, stream>>>(deg, N);
    k_count<<<(E + 255) / 256, 256, 0, stream>>>(dstp, deg, E);
    k_scan1<<<nb, 256, 0, stream>>>(deg, rowstart, bsum, N);
    k_scan2<<<1, 256, 0, stream>>>(bsum, nb);
    k_scan3<<<nb, 256, 0, stream>>>(rowstart, cursor, bsum, N, E + N);
    k_scatter<<<(E + N + 255) / 256, 256, 0, stream>>>(srcp, dstp, cursor, colarr, E, N);

    // layer 1: GEMM (128x128 tiles, 2 heads per y-block, double-buffered) + fused attn coef
    k_gemm_gat<<<dim3(mt128, 2), 256, 0, stream>>>(x, W1, asrc1, adst1, hb, es, ed, N, 128);
    k_gat_aggregate<<<nwb, 256, 0, stream>>>(hb, es, ed, rowstart, colarr, b1, g1, be1, h_small, N);

    // layer 2
    k_gemm_gat<<<dim3(mt128, 2), 256, 0, stream>>>(h_small, W2, asrc2, adst2, hb, es, ed, N, 64);
    k_gat_aggregate<<<nwb, 256, 0, stream>>>(hb, es, ed, rowstart, colarr, b2, g2, be2, h_small, N);

    // output projection (fp32, 128x128 tile, double-buffered)
    k_gemm<<<dim3(mt128, 1), 256, 0, stream>>>(h_small, Wo, bo, (float*)d_out, N, 128, 64);
}

// Round 9
// 404.695 us; speedup vs baseline: 1.2160x; 1.2160x over previous
//
#include <hip/hip_runtime.h>

#define NHEADS 4
#define NEG_SLOPE 0.2f
#define EPS_LN 1e-5f

typedef __attribute__((ext_vector_type(8))) short bf16x8;
typedef __attribute__((ext_vector_type(4))) float f32x4;

// ---------------- CSR build ----------------
__global__ __launch_bounds__(256) void k_init_deg(int* __restrict__ deg, int n) {
    int i = blockIdx.x * 256 + threadIdx.x;
    if (i < n) deg[i] = 1;  // self-loop
}

__global__ __launch_bounds__(256) void k_count(const int* __restrict__ dst, int* __restrict__ deg, int e) {
    int i = blockIdx.x * 256 + threadIdx.x;
    if (i < e) atomicAdd(&deg[dst[i]], 1);
}

__global__ __launch_bounds__(256) void k_scan1(const int* __restrict__ deg, int* __restrict__ rs,
                                               int* __restrict__ bsum, int n) {
    __shared__ int tmp[256];
    int tx = threadIdx.x;
    int i = blockIdx.x * 256 + tx;
    int v = (i < n) ? deg[i] : 0;
    tmp[tx] = v;
    __syncthreads();
    for (int off = 1; off < 256; off <<= 1) {
        int t = (tx >= off) ? tmp[tx - off] : 0;
        __syncthreads();
        tmp[tx] += t;
        __syncthreads();
    }
    if (i < n) rs[i] = tmp[tx] - v;
    if (tx == 255) bsum[blockIdx.x] = tmp[255];
}

__global__ __launch_bounds__(256) void k_scan2(int* __restrict__ bsum, int nb) {
    __shared__ int tmp[256];
    int tx = threadIdx.x;
    int v = (tx < nb) ? bsum[tx] : 0;
    tmp[tx] = v;
    __syncthreads();
    for (int off = 1; off < 256; off <<= 1) {
        int t = (tx >= off) ? tmp[tx - off] : 0;
        __syncthreads();
        tmp[tx] += t;
        __syncthreads();
    }
    if (tx < nb) bsum[tx] = tmp[tx] - v;
}

__global__ __launch_bounds__(256) void k_scan3(int* __restrict__ rs, int* __restrict__ cur,
                                               const int* __restrict__ bsum, int n, int total) {
    int i = blockIdx.x * 256 + threadIdx.x;
    if (i < n) {
        int r = rs[i] + bsum[blockIdx.x];
        rs[i] = r;
        cur[i] = r;
    }
    if (i == 0) rs[n] = total;
}

__global__ __launch_bounds__(256) void k_scatter(const int* __restrict__ src, const int* __restrict__ dst,
                                                 int* __restrict__ cur, int* __restrict__ col, int e, int n) {
    int i = blockIdx.x * 256 + threadIdx.x;
    if (i < e + n) {
        int s, d;
        if (i < e) { s = src[i]; d = dst[i]; }
        else       { s = i - e;  d = i - e;  }
        int p = atomicAdd(&cur[d], 1);
        col[p] = s;
    }
}

__device__ __forceinline__ unsigned short cvt_bf16(float x) {
    unsigned u = __float_as_uint(x);
    u += 0x7fffu + ((u >> 16) & 1u);
    return (unsigned short)(u >> 16);
}

// ---------------- MFMA bf16 GEMM -> bf16 h + fused attention coefficients ----------------
// C[M,256] = A[M,K]_fp32 @ B[K,256]_fp32 with bf16 MFMA (fp32 accumulate).
// Grid (ceil(M/128), 2): block = 128 rows x 128 cols (= heads {2y, 2y+1}). K fully resident:
// B staged ONCE to LDS transposed bf16 (ds_read_b128 fragments, 272B stride -> 2-way = free);
// A fragments read directly from global fp32 (dense 32B/lane segments) + in-reg cvt. One barrier.
// Wave w: rows 64*(w>>1), cols 64*(w&1) = one full head -> es/ed via 16-lane xor butterfly.
// MFMA layouts (verified, learn_hip m89/m91/m120): A[m=lane&15][k=quad*8+j];
// B[k=quad*8+j][n=lane&15]; C/D col=lane&15, row=quad*4+reg.
__global__ __launch_bounds__(256) void k_gemm_gat(const float* __restrict__ A, const float* __restrict__ B,
                                                  const float* __restrict__ asrc, const float* __restrict__ adst,
                                                  unsigned short* __restrict__ Hb16, float* __restrict__ es,
                                                  float* __restrict__ ed, int M, int K) {
    __shared__ unsigned short Bt[128][136];   // [n][k] bf16, pad 136 (16B-mult, non-pow2)
    int tid = threadIdx.x;
    int m0 = blockIdx.x * 128;
    int n0 = blockIdx.y * 128;
    // stage B transposed + cvt (reads coalesced over n)
    {
        int n = (tid & 31) * 4;
        for (int k = tid >> 5; k < K; k += 8) {
            float4 b4 = *(const float4*)&B[(size_t)k * 256 + n0 + n];
            Bt[n + 0][k] = cvt_bf16(b4.x);
            Bt[n + 1][k] = cvt_bf16(b4.y);
            Bt[n + 2][k] = cvt_bf16(b4.z);
            Bt[n + 3][k] = cvt_bf16(b4.w);
        }
    }
    __syncthreads();
    int w = tid >> 6, lane = tid & 63;
    int quad = lane >> 4, col16 = lane & 15;
    int mw = m0 + (w >> 1) * 64;
    int ch = w & 1;
    int head = blockIdx.y * 2 + ch;
    f32x4 acc[4][4] = {};
    int kc = K >> 5;
    for (int c = 0; c < kc; c++) {
        int kb = c * 32 + quad * 8;
        bf16x8 afr[4], bfr[4];
#pragma unroll
        for (int i = 0; i < 4; i++) {
            int row = mw + i * 16 + col16;
            if (row >= M) row = M - 1;          // clamp; results guarded at write
            const float* ap = &A[(size_t)row * K + kb];
            float4 a0 = *(const float4*)ap;
            float4 a1 = *(const float4*)(ap + 4);
            bf16x8 t;
            t[0] = (short)cvt_bf16(a0.x); t[1] = (short)cvt_bf16(a0.y);
            t[2] = (short)cvt_bf16(a0.z); t[3] = (short)cvt_bf16(a0.w);
            t[4] = (short)cvt_bf16(a1.x); t[5] = (short)cvt_bf16(a1.y);
            t[6] = (short)cvt_bf16(a1.z); t[7] = (short)cvt_bf16(a1.w);
            afr[i] = t;
        }
#pragma unroll
        for (int j = 0; j < 4; j++) {
            int n = ch * 64 + j * 16 + col16;
            bfr[j] = *(const bf16x8*)&Bt[n][kb];
        }
#pragma unroll
        for (int i = 0; i < 4; i++)
#pragma unroll
            for (int j = 0; j < 4; j++)
                acc[i][j] = __builtin_amdgcn_mfma_f32_16x16x32_bf16(afr[i], bfr[j], acc[i][j], 0, 0, 0);
    }
    // epilogue: es/ed (fp32-exact over bf16-rounded inputs) + bf16 h stores
    float av[4], dv[4];
#pragma unroll
    for (int j = 0; j < 4; j++) {
        av[j] = asrc[head * 64 + j * 16 + col16];
        dv[j] = adst[head * 64 + j * 16 + col16];
    }
#pragma unroll
    for (int i = 0; i < 4; i++) {
#pragma unroll
        for (int r = 0; r < 4; r++) {
            int m = mw + i * 16 + quad * 4 + r;
            float se = acc[i][0][r] * av[0] + acc[i][1][r] * av[1]
                     + acc[i][2][r] * av[2] + acc[i][3][r] * av[3];
            float sd = acc[i][0][r] * dv[0] + acc[i][1][r] * dv[1]
                     + acc[i][2][r] * dv[2] + acc[i][3][r] * dv[3];
            se += __shfl_xor(se, 1, 64); sd += __shfl_xor(sd, 1, 64);
            se += __shfl_xor(se, 2, 64); sd += __shfl_xor(sd, 2, 64);
            se += __shfl_xor(se, 4, 64); sd += __shfl_xor(sd, 4, 64);
            se += __shfl_xor(se, 8, 64); sd += __shfl_xor(sd, 8, 64);
            if (m < M) {
#pragma unroll
                for (int j = 0; j < 4; j++)
                    Hb16[(size_t)m * 256 + head * 64 + j * 16 + col16] = cvt_bf16(acc[i][j][r]);
                if (col16 == 0) { es[m * 4 + head] = se; ed[m * 4 + head] = sd; }
            }
        }
    }
}

// ---------------- MFMA bf16 GEMM with bias, fp32 out (output projection) ----------------
// C[M,128] = A[M,K]_fp32 @ B[K,128]_fp32 + bias. Grid (ceil(M/128)). Same structure.
__global__ __launch_bounds__(256) void k_gemm(const float* __restrict__ A, const float* __restrict__ B,
                                              const float* __restrict__ bias, float* __restrict__ C,
                                              int M, int Nn, int K) {
    __shared__ unsigned short Bt[128][136];
    int tid = threadIdx.x;
    int m0 = blockIdx.x * 128;
    {
        int n = (tid & 31) * 4;
        for (int k = tid >> 5; k < K; k += 8) {
            float4 b4 = *(const float4*)&B[(size_t)k * Nn + n];
            Bt[n + 0][k] = cvt_bf16(b4.x);
            Bt[n + 1][k] = cvt_bf16(b4.y);
            Bt[n + 2][k] = cvt_bf16(b4.z);
            Bt[n + 3][k] = cvt_bf16(b4.w);
        }
    }
    __syncthreads();
    int w = tid >> 6, lane = tid & 63;
    int quad = lane >> 4, col16 = lane & 15;
    int mw = m0 + (w >> 1) * 64;
    int ch = w & 1;
    f32x4 acc[4][4] = {};
    int kc = K >> 5;
    for (int c = 0; c < kc; c++) {
        int kb = c * 32 + quad * 8;
        bf16x8 afr[4], bfr[4];
#pragma unroll
        for (int i = 0; i < 4; i++) {
            int row = mw + i * 16 + col16;
            if (row >= M) row = M - 1;
            const float* ap = &A[(size_t)row * K + kb];
            float4 a0 = *(const float4*)ap;
            float4 a1 = *(const float4*)(ap + 4);
            bf16x8 t;
            t[0] = (short)cvt_bf16(a0.x); t[1] = (short)cvt_bf16(a0.y);
            t[2] = (short)cvt_bf16(a0.z); t[3] = (short)cvt_bf16(a0.w);
            t[4] = (short)cvt_bf16(a1.x); t[5] = (short)cvt_bf16(a1.y);
            t[6] = (short)cvt_bf16(a1.z); t[7] = (short)cvt_bf16(a1.w);
            afr[i] = t;
        }
#pragma unroll
        for (int j = 0; j < 4; j++) {
            int n = ch * 64 + j * 16 + col16;
            bfr[j] = *(const bf16x8*)&Bt[n][kb];
        }
#pragma unroll
        for (int i = 0; i < 4; i++)
#pragma unroll
            for (int j = 0; j < 4; j++)
                acc[i][j] = __builtin_amdgcn_mfma_f32_16x16x32_bf16(afr[i], bfr[j], acc[i][j], 0, 0, 0);
    }
    float bv[4];
#pragma unroll
    for (int j = 0; j < 4; j++) bv[j] = bias[ch * 64 + j * 16 + col16];
#pragma unroll
    for (int i = 0; i < 4; i++) {
#pragma unroll
        for (int r = 0; r < 4; r++) {
            int m = mw + i * 16 + quad * 4 + r;
            if (m < M) {
#pragma unroll
                for (int j = 0; j < 4; j++)
                    C[(size_t)m * Nn + ch * 64 + j * 16 + col16] = acc[i][j][r] + bv[j];
            }
        }
    }
}

// ---------------- fused GAT aggregate (bf16 gather) + head-mean + bias + LN + ReLU ----------------
// one wave per destination node; lane = (head, channel-quad). Unroll-4 with hoisted
// loads: 4 independent col->(es,Hb) chains in flight per wave for gather MLP.
__global__ __launch_bounds__(256) void k_gat_aggregate(const unsigned* __restrict__ Hb, const float* __restrict__ es,
                                                       const float* __restrict__ ed, const int* __restrict__ rs,
                                                       const int* __restrict__ col, const float* __restrict__ b,
                                                       const float* __restrict__ g, const float* __restrict__ be,
                                                       float* __restrict__ out, int n) {
    int node = blockIdx.x * 4 + (threadIdx.x >> 6);
    int lane = threadIdx.x & 63;
    if (node >= n) return;
    int head = lane >> 4;
    int cp = lane & 15;
    float edv = ed[node * 4 + head];
    float acc0 = 0.f, acc1 = 0.f, acc2 = 0.f, acc3 = 0.f, den = 0.f;
    int i0 = rs[node], i1 = rs[node + 1];
    int i = i0;
    for (; i + 3 < i1; i += 4) {
        int s0 = col[i], s1 = col[i + 1], s2 = col[i + 2], s3 = col[i + 3];
        float e0 = es[s0 * 4 + head];
        float e1 = es[s1 * 4 + head];
        float e2 = es[s2 * 4 + head];
        float e3 = es[s3 * 4 + head];
        uint2 u0 = *(const uint2*)&Hb[(size_t)s0 * 128 + lane * 2];
        uint2 u1 = *(const uint2*)&Hb[(size_t)s1 * 128 + lane * 2];
        uint2 u2 = *(const uint2*)&Hb[(size_t)s2 * 128 + lane * 2];
        uint2 u3 = *(const uint2*)&Hb[(size_t)s3 * 128 + lane * 2];
        e0 += edv; e1 += edv; e2 += edv; e3 += edv;
        e0 = fmaxf(e0, NEG_SLOPE * e0);
        e1 = fmaxf(e1, NEG_SLOPE * e1);
        e2 = fmaxf(e2, NEG_SLOPE * e2);
        e3 = fmaxf(e3, NEG_SLOPE * e3);
        float w0 = __expf(e0), w1 = __expf(e1), w2 = __expf(e2), w3 = __expf(e3);
        acc0 += w0 * __uint_as_float(u0.x << 16);
        acc1 += w0 * __uint_as_float(u0.x & 0xffff0000u);
        acc2 += w0 * __uint_as_float(u0.y << 16);
        acc3 += w0 * __uint_as_float(u0.y & 0xffff0000u);
        acc0 += w1 * __uint_as_float(u1.x << 16);
        acc1 += w1 * __uint_as_float(u1.x & 0xffff0000u);
        acc2 += w1 * __uint_as_float(u1.y << 16);
        acc3 += w1 * __uint_as_float(u1.y & 0xffff0000u);
        acc0 += w2 * __uint_as_float(u2.x << 16);
        acc1 += w2 * __uint_as_float(u2.x & 0xffff0000u);
        acc2 += w2 * __uint_as_float(u2.y << 16);
        acc3 += w2 * __uint_as_float(u2.y & 0xffff0000u);
        acc0 += w3 * __uint_as_float(u3.x << 16);
        acc1 += w3 * __uint_as_float(u3.x & 0xffff0000u);
        acc2 += w3 * __uint_as_float(u3.y << 16);
        acc3 += w3 * __uint_as_float(u3.y & 0xffff0000u);
        den += w0 + w1 + w2 + w3;
    }
    for (; i < i1; i++) {
        int s0 = col[i];
        float e0 = es[s0 * 4 + head] + edv;
        uint2 u0 = *(const uint2*)&Hb[(size_t)s0 * 128 + lane * 2];
        e0 = fmaxf(e0, NEG_SLOPE * e0);
        float w0 = __expf(e0);
        acc0 += w0 * __uint_as_float(u0.x << 16);
        acc1 += w0 * __uint_as_float(u0.x & 0xffff0000u);
        acc2 += w0 * __uint_as_float(u0.y << 16);
        acc3 += w0 * __uint_as_float(u0.y & 0xffff0000u);
        den += w0;
    }
    // softmax-normalize own head, then mean over heads via xor-16/32 butterflies
    float rd = 1.f / den;
    float r0 = acc0 * rd, r1 = acc1 * rd, r2 = acc2 * rd, r3 = acc3 * rd;
    r0 += __shfl_xor(r0, 16, 64); r1 += __shfl_xor(r1, 16, 64);
    r2 += __shfl_xor(r2, 16, 64); r3 += __shfl_xor(r3, 16, 64);
    r0 += __shfl_xor(r0, 32, 64); r1 += __shfl_xor(r1, 32, 64);
    r2 += __shfl_xor(r2, 32, 64); r3 += __shfl_xor(r3, 32, 64);
    float4 bb = *(const float4*)&b[cp * 4];
    float v0 = 0.25f * r0 + bb.x;
    float v1 = 0.25f * r1 + bb.y;
    float v2 = 0.25f * r2 + bb.z;
    float v3 = 0.25f * r3 + bb.w;
    // LayerNorm over 64 channels: reduce within the 16-lane head group (groups identical)
    float s = v0 + v1 + v2 + v3;
    float q = v0 * v0 + v1 * v1 + v2 * v2 + v3 * v3;
    for (int off = 1; off < 16; off <<= 1) {
        s += __shfl_xor(s, off, 64);
        q += __shfl_xor(q, off, 64);
    }
    float mean = s * (1.f / 64.f);
    float var = q * (1.f / 64.f) - mean * mean;
    float rinv = rsqrtf(var + EPS_LN);
    float4 gg = *(const float4*)&g[cp * 4];
    float4 ee = *(const float4*)&be[cp * 4];
    if (head == 0) {
        float4 y;
        y.x = fmaxf((v0 - mean) * rinv * gg.x + ee.x, 0.f);
        y.y = fmaxf((v1 - mean) * rinv * gg.y + ee.y, 0.f);
        y.z = fmaxf((v2 - mean) * rinv * gg.z + ee.z, 0.f);
        y.w = fmaxf((v3 - mean) * rinv * gg.w + ee.w, 0.f);
        *(float4*)&out[(size_t)node * 64 + cp * 4] = y;
    }
}

// ---------------- launch ----------------
extern "C" void kernel_launch(void* const* d_in, const int* in_sizes, int n_in,
                              void* d_out, int out_size, void* d_ws, size_t ws_size,
                              hipStream_t stream) {
    const float* x     = (const float*)d_in[0];
    const int*   eidx  = (const int*)d_in[1];
    const float* W1    = (const float*)d_in[2];
    const float* asrc1 = (const float*)d_in[3];
    const float* adst1 = (const float*)d_in[4];
    const float* b1    = (const float*)d_in[5];
    const float* g1    = (const float*)d_in[6];
    const float* be1   = (const float*)d_in[7];
    const float* W2    = (const float*)d_in[8];
    const float* asrc2 = (const float*)d_in[9];
    const float* adst2 = (const float*)d_in[10];
    const float* b2    = (const float*)d_in[11];
    const float* g2    = (const float*)d_in[12];
    const float* be2   = (const float*)d_in[13];
    const float* Wo    = (const float*)d_in[14];
    const float* bo    = (const float*)d_in[15];

    const int N = in_sizes[0] / 128;
    const int E = in_sizes[1] / 2;
    const int* srcp = eidx;
    const int* dstp = eidx + E;

    // workspace layout
    unsigned* hb   = (unsigned*)d_ws;                       // [N*128] bf16x2 (h1, then h3)
    float* h_small = (float*)(hb + (size_t)N * 128);        // [N,64] fp32 (h2, then h4)
    float* es      = h_small + (size_t)N * 64;              // [N,4]
    float* ed      = es + (size_t)N * 4;                    // [N,4]
    int* deg       = (int*)(ed + (size_t)N * 4);            // [N]
    int* rowstart  = deg + N;                               // [N+1]
    int* cursor    = rowstart + (N + 1);                    // [N]
    int* colarr    = cursor + N;                            // [E+N]
    int* bsum      = colarr + (size_t)(E + N);              // [<=256]

    const int nb = (N + 255) / 256;
    const int nwb = (N + 3) / 4;
    const int mt128 = (N + 127) / 128;

    // CSR build
    k_init_deg<<<nb, 256, 0, stream>>>(deg, N);
    k_count<<<(E + 255) / 256, 256, 0, stream>>>(dstp, deg, E);
    k_scan1<<<nb, 256, 0, stream>>>(deg, rowstart, bsum, N);
    k_scan2<<<1, 256, 0, stream>>>(bsum, nb);
    k_scan3<<<nb, 256, 0, stream>>>(rowstart, cursor, bsum, N, E + N);
    k_scatter<<<(E + N + 255) / 256, 256, 0, stream>>>(srcp, dstp, cursor, colarr, E, N);

    // layer 1: MFMA GEMM (whole-K resident, 1 barrier) + fused attn coef
    k_gemm_gat<<<dim3(mt128, 2), 256, 0, stream>>>(x, W1, asrc1, adst1,
                                                   (unsigned short*)hb, es, ed, N, 128);
    k_gat_aggregate<<<nwb, 256, 0, stream>>>(hb, es, ed, rowstart, colarr, b1, g1, be1, h_small, N);

    // layer 2
    k_gemm_gat<<<dim3(mt128, 2), 256, 0, stream>>>(h_small, W2, asrc2, adst2,
                                                   (unsigned short*)hb, es, ed, N, 64);
    k_gat_aggregate<<<nwb, 256, 0, stream>>>(hb, es, ed, rowstart, colarr, b2, g2, be2, h_small, N);

    // output projection (MFMA, fp32 out + bias)
    k_gemm<<<dim3(mt128, 1), 256, 0, stream>>>(h_small, Wo, bo, (float*)d_out, N, 128, 64);
}